// Round 4
// baseline (31.944 us; speedup 1.0000x reference)
//
#include <hip/hip_runtime.h>

#define DD 6
#define SDIM 17
#define CAPF 20.0f
#define BIGF 1e30f

__device__ __forceinline__ void project_row(const float q[DD], const float w[DD],
                                            float o[DD])
{
    float a[DD], r[DD], wq[DD], w2[DD];
    float total = 0.f;
#pragma unroll
    for (int i = 0; i < DD; ++i) {
        a[i]  = fabsf(q[i]);
        wq[i] = w[i] * a[i];
        w2[i] = w[i] * w[i];
        total += wq[i];
        r[i]  = (w[i] > 0.f) ? (a[i] / w[i]) : BIGF;
    }

    // sort (r, wq, w2) descending by r — 15-cswap unrolled bubble network
#pragma unroll
    for (int i = 0; i < DD - 1; ++i) {
#pragma unroll
        for (int j = 0; j < DD - 1 - i; ++j) {
            bool sw = r[j] < r[j + 1];
            float t0 = r[j], t1 = wq[j], t2 = w2[j];
            r[j]  = sw ? r[j + 1]  : r[j];
            wq[j] = sw ? wq[j + 1] : wq[j];
            w2[j] = sw ? w2[j + 1] : w2[j];
            r[j + 1]  = sw ? t0 : r[j + 1];
            wq[j + 1] = sw ? t1 : wq[j + 1];
            w2[j + 1] = sw ? t2 : w2[j + 1];
        }
    }

    float cwq = 0.f, cw2 = 0.f;
    float lamk[DD];
    int m = 0;
#pragma unroll
    for (int k = 0; k < DD; ++k) {
        cwq += wq[k];
        cw2 += w2[k];
        float safe = (cw2 > 0.f) ? cw2 : 1.f;
        lamk[k] = (cwq - CAPF) / safe;
        bool valid = (r[k] > lamk[k]) && (cw2 > 0.f);
        m += valid ? 1 : 0;
    }
    int ks = m - 1;
    if (ks < 0) ks = 0;
    float lam = lamk[0];
#pragma unroll
    for (int k = 1; k < DD; ++k) lam = (ks == k) ? lamk[k] : lam;
    lam = (total > CAPF) ? fmaxf(lam, 0.f) : 0.f;

#pragma unroll
    for (int i = 0; i < DD; ++i) {
        float mag = fmaxf(a[i] - lam * w[i], 0.f);
        float sgn = (q[i] > 0.f) ? 1.f : ((q[i] < 0.f) ? -1.f : 0.f);
        o[i] = sgn * mag;
    }
}

__global__ __launch_bounds__(256) void proj_wl1_kernel(
    const float* __restrict__ x, const float* __restrict__ s,
    float* __restrict__ out, int B)
{
    const size_t p = (size_t)blockIdx.x * blockDim.x + threadIdx.x;  // row pair
    const size_t r0 = 2 * p;
    if (r0 >= (size_t)B) return;

    float q0[DD], q1[DD], w0[DD], w1[DD], o0[DD], o1[DD];

    if (r0 + 1 < (size_t)B) {
        // ---- x: 2 rows = 48 B = exactly 3 aligned float4 ----
        const float4* xv = reinterpret_cast<const float4*>(x);
        float4 a0 = xv[3 * p + 0];
        float4 a1 = xv[3 * p + 1];
        float4 a2 = xv[3 * p + 2];
        q0[0] = a0.x; q0[1] = a0.y; q0[2] = a0.z; q0[3] = a0.w;
        q0[4] = a1.x; q0[5] = a1.y;
        q1[0] = a1.z; q1[1] = a1.w;
        q1[2] = a2.x; q1[3] = a2.y; q1[4] = a2.z; q1[5] = a2.w;

        // ---- s: cols 11..16 of each row, scalar (rows only 4-B aligned) ----
        const float* sp0 = s + r0 * SDIM + 11;
        const float* sp1 = sp0 + SDIM;
#pragma unroll
        for (int i = 0; i < DD; ++i) w0[i] = fabsf(sp0[i]);
#pragma unroll
        for (int i = 0; i < DD; ++i) w1[i] = fabsf(sp1[i]);

        project_row(q0, w0, o0);
        project_row(q1, w1, o1);

        // ---- out: 2 rows = 3 aligned float4 ----
        float4* ov = reinterpret_cast<float4*>(out);
        ov[3 * p + 0] = make_float4(o0[0], o0[1], o0[2], o0[3]);
        ov[3 * p + 1] = make_float4(o0[4], o0[5], o1[0], o1[1]);
        ov[3 * p + 2] = make_float4(o1[2], o1[3], o1[4], o1[5]);
    } else {
        // odd tail row
        const float* xp = x + r0 * DD;
        const float* sp = s + r0 * SDIM + 11;
#pragma unroll
        for (int i = 0; i < DD; ++i) q0[i] = xp[i];
#pragma unroll
        for (int i = 0; i < DD; ++i) w0[i] = fabsf(sp[i]);
        project_row(q0, w0, o0);
        float* op = out + r0 * DD;
#pragma unroll
        for (int i = 0; i < DD; ++i) op[i] = o0[i];
    }
}

extern "C" void kernel_launch(void* const* d_in, const int* in_sizes, int n_in,
                              void* d_out, int out_size, void* d_ws, size_t ws_size,
                              hipStream_t stream)
{
    const float* x = (const float*)d_in[0];
    const float* s = (const float*)d_in[1];
    float* out = (float*)d_out;
    int B = in_sizes[0] / DD;

    const int block = 256;
    int pairs = (B + 1) / 2;
    int grid = (pairs + block - 1) / block;
    proj_wl1_kernel<<<grid, block, 0, stream>>>(x, s, out, B);
}

// Round 6
// 24.453 us; speedup vs baseline: 1.3063x; 1.3063x over previous
//
#include <hip/hip_runtime.h>

#define DD 6
#define SDIM 17
#define CAPF 20.0f
#define BIGF 1e30f

typedef float vf2 __attribute__((ext_vector_type(2)));

__global__ __launch_bounds__(256) void proj_wl1_kernel(
    const float* __restrict__ x, const float* __restrict__ s,
    float* __restrict__ out, int B)
{
    int b = blockIdx.x * blockDim.x + threadIdx.x;
    if (b >= B) return;

    // ---- s loads first (long pole: 68-B-stride scalar dwords) ----
    const float* sp = s + (size_t)b * SDIM + 11;
    float w[DD];
#pragma unroll
    for (int i = 0; i < DD; ++i) w[i] = fabsf(sp[i]);

    // ---- q: 24-B rows, 8-B aligned -> 3x float2 ----
    const float* xp = x + (size_t)b * DD;
    vf2 q01 = *reinterpret_cast<const vf2*>(xp + 0);
    vf2 q23 = *reinterpret_cast<const vf2*>(xp + 2);
    vf2 q45 = *reinterpret_cast<const vf2*>(xp + 4);
    float q[DD] = {q01.x, q01.y, q23.x, q23.y, q45.x, q45.y};

    // ---- closed-form weighted-L1 projection (exact reference semantics) ----
    float a[DD], r[DD], wq[DD], w2[DD];
    float total = 0.f;
#pragma unroll
    for (int i = 0; i < DD; ++i) {
        a[i]  = fabsf(q[i]);
        wq[i] = w[i] * a[i];
        w2[i] = w[i] * w[i];
        total += wq[i];
        r[i]  = (w[i] > 0.f) ? (a[i] / w[i]) : BIGF;
    }

    // sort (r, wq, w2) descending by r — 15-cswap unrolled bubble network
#pragma unroll
    for (int i = 0; i < DD - 1; ++i) {
#pragma unroll
        for (int j = 0; j < DD - 1 - i; ++j) {
            bool sw = r[j] < r[j + 1];
            float t0 = r[j], t1 = wq[j], t2 = w2[j];
            r[j]  = sw ? r[j + 1]  : r[j];
            wq[j] = sw ? wq[j + 1] : wq[j];
            w2[j] = sw ? w2[j + 1] : w2[j];
            r[j + 1]  = sw ? t0 : r[j + 1];
            wq[j + 1] = sw ? t1 : wq[j + 1];
            w2[j + 1] = sw ? t2 : w2[j + 1];
        }
    }

    float cwq = 0.f, cw2 = 0.f;
    float lamk[DD];
    int m = 0;
#pragma unroll
    for (int k = 0; k < DD; ++k) {
        cwq += wq[k];
        cw2 += w2[k];
        float safe = (cw2 > 0.f) ? cw2 : 1.f;
        lamk[k] = (cwq - CAPF) / safe;
        bool valid = (r[k] > lamk[k]) && (cw2 > 0.f);
        m += valid ? 1 : 0;
    }
    int ks = m - 1;
    if (ks < 0) ks = 0;
    float lam = lamk[0];
#pragma unroll
    for (int k = 1; k < DD; ++k) lam = (ks == k) ? lamk[k] : lam;
    lam = (total > CAPF) ? fmaxf(lam, 0.f) : 0.f;

    float o[DD];
#pragma unroll
    for (int i = 0; i < DD; ++i) {
        float mag = fmaxf(a[i] - lam * w[i], 0.f);
        float sgn = (q[i] > 0.f) ? 1.f : ((q[i] < 0.f) ? -1.f : 0.f);
        o[i] = sgn * mag;
    }

    // ---- nontemporal float2 stores: out is never re-read; skip cache allocate ----
    float* op = out + (size_t)b * DD;
    vf2 o01 = {o[0], o[1]};
    vf2 o23 = {o[2], o[3]};
    vf2 o45 = {o[4], o[5]};
    __builtin_nontemporal_store(o01, reinterpret_cast<vf2*>(op + 0));
    __builtin_nontemporal_store(o23, reinterpret_cast<vf2*>(op + 2));
    __builtin_nontemporal_store(o45, reinterpret_cast<vf2*>(op + 4));
}

extern "C" void kernel_launch(void* const* d_in, const int* in_sizes, int n_in,
                              void* d_out, int out_size, void* d_ws, size_t ws_size,
                              hipStream_t stream)
{
    const float* x = (const float*)d_in[0];
    const float* s = (const float*)d_in[1];
    float* out = (float*)d_out;
    int B = in_sizes[0] / DD;

    const int block = 256;
    int grid = (B + block - 1) / block;
    proj_wl1_kernel<<<grid, block, 0, stream>>>(x, s, out, B);
}

// Round 7
// 23.721 us; speedup vs baseline: 1.3467x; 1.0309x over previous
//
#include <hip/hip_runtime.h>

#define DD 6
#define SDIM 17
#define CAPF 20.0f
#define BIGF 1e30f

__global__ __launch_bounds__(256) void proj_wl1_kernel(
    const float* __restrict__ x, const float* __restrict__ s,
    float* __restrict__ out, int B)
{
    int b = blockIdx.x * blockDim.x + threadIdx.x;
    if (b >= B) return;

    // ---- s loads first (long pole: 68-B-stride scalar dwords) ----
    const float* sp = s + (size_t)b * SDIM + 11;
    float w[DD];
#pragma unroll
    for (int i = 0; i < DD; ++i) w[i] = fabsf(sp[i]);

    // ---- q: 24-B rows, 8-B aligned -> 3x float2 ----
    const float* xp = x + (size_t)b * DD;
    float2 q01 = *reinterpret_cast<const float2*>(xp + 0);
    float2 q23 = *reinterpret_cast<const float2*>(xp + 2);
    float2 q45 = *reinterpret_cast<const float2*>(xp + 4);
    float q[DD] = {q01.x, q01.y, q23.x, q23.y, q45.x, q45.y};

    // ---- closed-form weighted-L1 projection (exact reference semantics) ----
    float a[DD], r[DD], wq[DD], w2[DD];
    float total = 0.f;
#pragma unroll
    for (int i = 0; i < DD; ++i) {
        a[i]  = fabsf(q[i]);
        wq[i] = w[i] * a[i];
        w2[i] = w[i] * w[i];
        total += wq[i];
        r[i]  = (w[i] > 0.f) ? (a[i] / w[i]) : BIGF;
    }

    // sort (r, wq, w2) descending by r — 15-cswap unrolled bubble network
#pragma unroll
    for (int i = 0; i < DD - 1; ++i) {
#pragma unroll
        for (int j = 0; j < DD - 1 - i; ++j) {
            bool sw = r[j] < r[j + 1];
            float t0 = r[j], t1 = wq[j], t2 = w2[j];
            r[j]  = sw ? r[j + 1]  : r[j];
            wq[j] = sw ? wq[j + 1] : wq[j];
            w2[j] = sw ? w2[j + 1] : w2[j];
            r[j + 1]  = sw ? t0 : r[j + 1];
            wq[j + 1] = sw ? t1 : wq[j + 1];
            w2[j + 1] = sw ? t2 : w2[j + 1];
        }
    }

    float cwq = 0.f, cw2 = 0.f;
    float lamk[DD];
    int m = 0;
#pragma unroll
    for (int k = 0; k < DD; ++k) {
        cwq += wq[k];
        cw2 += w2[k];
        float safe = (cw2 > 0.f) ? cw2 : 1.f;
        lamk[k] = (cwq - CAPF) / safe;
        bool valid = (r[k] > lamk[k]) && (cw2 > 0.f);
        m += valid ? 1 : 0;
    }
    int ks = m - 1;
    if (ks < 0) ks = 0;
    float lam = lamk[0];
#pragma unroll
    for (int k = 1; k < DD; ++k) lam = (ks == k) ? lamk[k] : lam;
    lam = (total > CAPF) ? fmaxf(lam, 0.f) : 0.f;

    float o[DD];
#pragma unroll
    for (int i = 0; i < DD; ++i) {
        float mag = fmaxf(a[i] - lam * w[i], 0.f);
        float sgn = (q[i] > 0.f) ? 1.f : ((q[i] < 0.f) ? -1.f : 0.f);
        o[i] = sgn * mag;
    }

    float* op = out + (size_t)b * DD;
    *reinterpret_cast<float2*>(op + 0) = make_float2(o[0], o[1]);
    *reinterpret_cast<float2*>(op + 2) = make_float2(o[2], o[3]);
    *reinterpret_cast<float2*>(op + 4) = make_float2(o[4], o[5]);
}

extern "C" void kernel_launch(void* const* d_in, const int* in_sizes, int n_in,
                              void* d_out, int out_size, void* d_ws, size_t ws_size,
                              hipStream_t stream)
{
    const float* x = (const float*)d_in[0];
    const float* s = (const float*)d_in[1];
    float* out = (float*)d_out;
    int B = in_sizes[0] / DD;

    const int block = 256;
    int grid = (B + block - 1) / block;
    proj_wl1_kernel<<<grid, block, 0, stream>>>(x, s, out, B);
}